// Round 1
// baseline (135.875 us; speedup 1.0000x reference)
//
#include <hip/hip_runtime.h>
#include <cfloat>

// Emu3 VQ-VAE vector quantizer argmin:
//   hidden_state [1,4,4,48,48] f32  ->  x [9216,4] (channels-last)
//   embedding    [32768,4] f32
//   out[n] = argmin_k ( ||x_n||^2 + ||e_k||^2 - 2 x_n.e_k )   (first-min ties)
//
// Numerics replicate the reference rounding chain exactly:
//   x2,e2: rn mul-then-add sequential (no fma contraction)
//   dot  : sequential fma chain over d=0..3
//   dist : fl( fl(x2+e2) - 2*fl(dot) )  via fmaf(dot,-2,t1) (2*dot exact)

#define ROWS   12        // rows per block: 9216/12 = 768 blocks = 3 blocks/CU
#define TILE   2048      // codebook entries per LDS tile (32KB float4 + 8KB e2)
#define BLOCK  256
#define NK     32768

__global__ __launch_bounds__(BLOCK, 3)
void vq_argmin_kernel(const float* __restrict__ hs,
                      const float4* __restrict__ cb,
                      int* __restrict__ out)
{
    __shared__ float4 sE[TILE];
    __shared__ float  sE2[TILE];
    __shared__ float  sRD[4 * ROWS];
    __shared__ int    sRI[4 * ROWS];

    const int tid = threadIdx.x;
    const int rowbase = blockIdx.x * ROWS;

    float xr0[ROWS], xr1[ROWS], xr2[ROWS], xr3[ROWS];
    float x2[ROWS];
    float best[ROWS];
    int   bidx[ROWS];

    #pragma unroll
    for (int r = 0; r < ROWS; ++r) {
        int n = rowbase + r;
        int t = n / 2304;            // 2304 = 48*48
        int rem = n - t * 2304;
        const float* p = hs + t * 9216 + rem;   // t*4*2304 + c*2304 + rem
        float a0 = p[0], a1 = p[2304], a2 = p[4608], a3 = p[6912];
        xr0[r] = a0; xr1[r] = a1; xr2[r] = a2; xr3[r] = a3;
        x2[r] = __fadd_rn(__fadd_rn(__fadd_rn(__fmul_rn(a0, a0),
                                              __fmul_rn(a1, a1)),
                                    __fmul_rn(a2, a2)),
                          __fmul_rn(a3, a3));
        best[r] = FLT_MAX;
        bidx[r] = 0;
    }

    for (int tb = 0; tb < NK; tb += TILE) {
        // ---- stage tile into LDS (coalesced float4; e2 computed on the fly)
        #pragma unroll
        for (int i = 0; i < TILE / BLOCK; ++i) {
            int j = tid + i * BLOCK;
            float4 e = cb[tb + j];
            sE[j] = e;
            sE2[j] = __fadd_rn(__fadd_rn(__fadd_rn(__fmul_rn(e.x, e.x),
                                                   __fmul_rn(e.y, e.y)),
                                         __fmul_rn(e.z, e.z)),
                               __fmul_rn(e.w, e.w));
        }
        __syncthreads();

        // ---- compute: thread t owns entries {t, t+256, ...} (ascending k)
        #pragma unroll 2
        for (int i = 0; i < TILE / BLOCK; ++i) {
            int j = tid + i * BLOCK;
            float4 e = sE[j];
            float e2v = sE2[j];
            int kk = tb + j;
            #pragma unroll
            for (int r = 0; r < ROWS; ++r) {
                float dot = __builtin_fmaf(xr3[r], e.w,
                            __builtin_fmaf(xr2[r], e.z,
                            __builtin_fmaf(xr1[r], e.y,
                            __fmul_rn(xr0[r], e.x))));
                float t1 = __fadd_rn(x2[r], e2v);
                float d  = __builtin_fmaf(dot, -2.0f, t1);
                if (d < best[r]) { best[r] = d; bidx[r] = kk; }
            }
        }
        __syncthreads();
    }

    // ---- wave-level lexicographic (dist, idx) butterfly reduction
    #pragma unroll
    for (int r = 0; r < ROWS; ++r) {
        float d = best[r]; int i = bidx[r];
        #pragma unroll
        for (int off = 32; off >= 1; off >>= 1) {
            float d2 = __shfl_xor(d, off, 64);
            int   i2 = __shfl_xor(i, off, 64);
            if (d2 < d || (d2 == d && i2 < i)) { d = d2; i = i2; }
        }
        best[r] = d; bidx[r] = i;
    }

    int wave = tid >> 6;
    if ((tid & 63) == 0) {
        #pragma unroll
        for (int r = 0; r < ROWS; ++r) {
            sRD[wave * ROWS + r] = best[r];
            sRI[wave * ROWS + r] = bidx[r];
        }
    }
    __syncthreads();

    // ---- cross-wave reduce + write int32 indices
    if (tid < ROWS) {
        float d = sRD[tid]; int i = sRI[tid];
        #pragma unroll
        for (int w = 1; w < 4; ++w) {
            float d2 = sRD[w * ROWS + tid];
            int   i2 = sRI[w * ROWS + tid];
            if (d2 < d || (d2 == d && i2 < i)) { d = d2; i = i2; }
        }
        out[rowbase + tid] = i;
    }
}

extern "C" void kernel_launch(void* const* d_in, const int* in_sizes, int n_in,
                              void* d_out, int out_size, void* d_ws, size_t ws_size,
                              hipStream_t stream)
{
    const float*  hs = (const float*)d_in[0];    // [1,4,4,48,48]
    const float4* cb = (const float4*)d_in[1];   // [32768,4]
    int* out = (int*)d_out;                      // [9216] int32

    const int nrows = 9216;
    dim3 grid(nrows / ROWS), block(BLOCK);
    vq_argmin_kernel<<<grid, block, 0, stream>>>(hs, cb, out);
}

// Round 2
// 133.385 us; speedup vs baseline: 1.0187x; 1.0187x over previous
//
#include <hip/hip_runtime.h>
#include <cfloat>
#include <stdint.h>

// Emu3 VQ-VAE vector quantizer argmin (exact-rounding match to numpy ref):
//   x [9216,4] f32 (channels-last gather from [1,4,4,48,48])
//   e [32768,4] f32
//   out[n] = argmin_k fl( fl(x2+e2) - 2*fl(dot) ), first-min tie semantics.
//
// Round 2: double-buffered async global->LDS pipeline (global_load_lds w=16),
// one barrier per tile, ROWS=9 -> 1024 blocks = exactly 4 blocks/CU,
// LDS 2x16KB. e2 recomputed inline from staged float4 (exact same chain).

#define ROWS   9
#define TILE   1024
#define BLOCK  256
#define NK     32768
#define NTILE  (NK / TILE)     // 32
#define EPT    (TILE / BLOCK)  // 4

typedef const __attribute__((address_space(1))) void GAS;
typedef __attribute__((address_space(3))) void LAS;

#define STAGE_TILE(BUF, TB)                                                   \
    {                                                                         \
        _Pragma("unroll")                                                     \
        for (int c = 0; c < EPT; ++c) {                                       \
            int slot = c * BLOCK + tid;                                       \
            __builtin_amdgcn_global_load_lds((GAS*)(cb + (TB) + slot),        \
                                             (LAS*)(&BUF[slot]), 16, 0, 0);   \
        }                                                                     \
    }

#define COMPUTE_TILE(BUF, KBASE)                                              \
    {                                                                         \
        _Pragma("unroll")                                                     \
        for (int i = 0; i < EPT; ++i) {                                       \
            float4 e = BUF[tid + i * BLOCK];                                  \
            float e2v = __fadd_rn(__fadd_rn(__fadd_rn(__fmul_rn(e.x, e.x),    \
                                                      __fmul_rn(e.y, e.y)),   \
                                            __fmul_rn(e.z, e.z)),             \
                                  __fmul_rn(e.w, e.w));                       \
            int kk = (KBASE) + tid + i * BLOCK;                               \
            _Pragma("unroll")                                                 \
            for (int r = 0; r < ROWS; ++r) {                                  \
                float dot = __builtin_fmaf(xr3[r], e.w,                       \
                            __builtin_fmaf(xr2[r], e.z,                       \
                            __builtin_fmaf(xr1[r], e.y,                       \
                            __fmul_rn(xr0[r], e.x))));                        \
                float t1 = __fadd_rn(x2[r], e2v);                             \
                float d  = __builtin_fmaf(dot, -2.0f, t1);                    \
                if (d < best[r]) { best[r] = d; bidx[r] = kk; }               \
            }                                                                 \
        }                                                                     \
    }

__global__ __launch_bounds__(BLOCK, 4)
void vq_argmin_kernel(const float* __restrict__ hs,
                      const float4* __restrict__ cb,
                      int* __restrict__ out)
{
    __shared__ float4 sE0[TILE];
    __shared__ float4 sE1[TILE];
    __shared__ float  sRD[4 * ROWS];
    __shared__ int    sRI[4 * ROWS];

    const int tid = threadIdx.x;
    const int rowbase = blockIdx.x * ROWS;

    float xr0[ROWS], xr1[ROWS], xr2[ROWS], xr3[ROWS];
    float x2[ROWS];
    float best[ROWS];
    int   bidx[ROWS];

    #pragma unroll
    for (int r = 0; r < ROWS; ++r) {
        int n = rowbase + r;
        int t = n / 2304;                 // 2304 = 48*48
        int rem = n - t * 2304;
        const float* p = hs + t * 9216 + rem;   // + c*2304 per channel
        float a0 = p[0], a1 = p[2304], a2 = p[4608], a3 = p[6912];
        xr0[r] = a0; xr1[r] = a1; xr2[r] = a2; xr3[r] = a3;
        x2[r] = __fadd_rn(__fadd_rn(__fadd_rn(__fmul_rn(a0, a0),
                                              __fmul_rn(a1, a1)),
                                    __fmul_rn(a2, a2)),
                          __fmul_rn(a3, a3));
        best[r] = FLT_MAX;
        bidx[r] = 0;
    }

    // ---- software pipeline: stage t+1 async while computing t
    STAGE_TILE(sE0, 0);

    for (int t = 0; t < NTILE; t += 2) {
        __syncthreads();                        // sE0 (tile t) ready
        STAGE_TILE(sE1, (t + 1) * TILE);        // async into other buffer
        COMPUTE_TILE(sE0, t * TILE);
        __syncthreads();                        // sE1 (tile t+1) ready
        if (t + 2 < NTILE) STAGE_TILE(sE0, (t + 2) * TILE);
        COMPUTE_TILE(sE1, (t + 1) * TILE);
    }

    // ---- wave-level lexicographic (dist, idx) butterfly reduction
    #pragma unroll
    for (int r = 0; r < ROWS; ++r) {
        float d = best[r]; int i = bidx[r];
        #pragma unroll
        for (int off = 32; off >= 1; off >>= 1) {
            float d2 = __shfl_xor(d, off, 64);
            int   i2 = __shfl_xor(i, off, 64);
            if (d2 < d || (d2 == d && i2 < i)) { d = d2; i = i2; }
        }
        best[r] = d; bidx[r] = i;
    }

    int wave = tid >> 6;
    if ((tid & 63) == 0) {
        #pragma unroll
        for (int r = 0; r < ROWS; ++r) {
            sRD[wave * ROWS + r] = best[r];
            sRI[wave * ROWS + r] = bidx[r];
        }
    }
    __syncthreads();

    if (tid < ROWS) {
        float d = sRD[tid]; int i = sRI[tid];
        #pragma unroll
        for (int w = 1; w < 4; ++w) {
            float d2 = sRD[w * ROWS + tid];
            int   i2 = sRI[w * ROWS + tid];
            if (d2 < d || (d2 == d && i2 < i)) { d = d2; i = i2; }
        }
        out[rowbase + tid] = i;
    }
}

extern "C" void kernel_launch(void* const* d_in, const int* in_sizes, int n_in,
                              void* d_out, int out_size, void* d_ws, size_t ws_size,
                              hipStream_t stream)
{
    const float*  hs = (const float*)d_in[0];    // [1,4,4,48,48]
    const float4* cb = (const float4*)d_in[1];   // [32768,4]
    int* out = (int*)d_out;                      // [9216] int32

    const int nrows = 9216;
    dim3 grid(nrows / ROWS), block(BLOCK);
    vq_argmin_kernel<<<grid, block, 0, stream>>>(hs, cb, out);
}

// Round 3
// 126.812 us; speedup vs baseline: 1.0715x; 1.0518x over previous
//
#include <hip/hip_runtime.h>
#include <cfloat>

// Emu3 VQ-VAE vector quantizer argmin (exact-rounding match to numpy ref):
//   x [9216,4] f32 (channels-last gather from [1,4,4,48,48])
//   e [32768,4] f32
//   out[n] = argmin_k fl( fl(x2+e2) - 2*fl(dot) ), first-min tie semantics.
//
// Round 3: no LDS staging, no barriers in the K loop. Codebook is L2-resident
// (512 KB/XCD); each lane streams 4 float4 entries/chunk straight to VGPRs
// with manual next-chunk prefetch. ROWS=9 -> 1024 blocks = 4/CU exact.
// Rationale: round-2 counters showed VGPR_Count=52 < 63 live -> compiler was
// round-tripping arrays through AGPRs (v_accvgpr_*), ~2x VALU bloat.

#define ROWS   9
#define BLOCK  256
#define NK     32768
#define EPT    4                  // codebook entries per lane per chunk
#define CHUNK  (BLOCK * EPT)      // 1024 entries per chunk

__global__ __launch_bounds__(BLOCK, 4)
void vq_argmin_kernel(const float* __restrict__ hs,
                      const float4* __restrict__ cb,
                      int* __restrict__ out)
{
    __shared__ float sRD[4 * ROWS];
    __shared__ int   sRI[4 * ROWS];

    const int tid = threadIdx.x;
    const int rowbase = blockIdx.x * ROWS;

    float xr0[ROWS], xr1[ROWS], xr2[ROWS], xr3[ROWS];
    float x2[ROWS];
    float best[ROWS];
    int   bidx[ROWS];

    #pragma unroll
    for (int r = 0; r < ROWS; ++r) {
        int n = rowbase + r;
        int t = n / 2304;                 // 2304 = 48*48
        int rem = n - t * 2304;
        const float* p = hs + t * 9216 + rem;   // + c*2304 per channel
        float a0 = p[0], a1 = p[2304], a2 = p[4608], a3 = p[6912];
        xr0[r] = a0; xr1[r] = a1; xr2[r] = a2; xr3[r] = a3;
        x2[r] = __fadd_rn(__fadd_rn(__fadd_rn(__fmul_rn(a0, a0),
                                              __fmul_rn(a1, a1)),
                                    __fmul_rn(a2, a2)),
                          __fmul_rn(a3, a3));
        best[r] = FLT_MAX;
        bidx[r] = 0;
    }

    // ---- K loop: register-resident chunks, manual prefetch, no barriers
    float4 ce[EPT], ne[EPT];
    #pragma unroll
    for (int j = 0; j < EPT; ++j) ce[j] = cb[tid + j * BLOCK];

    for (int tb = 0; tb < NK; tb += CHUNK) {
        // prefetch next chunk (last iter re-reads current; discarded)
        int nb = tb + CHUNK < NK ? tb + CHUNK : tb;
        #pragma unroll
        for (int j = 0; j < EPT; ++j) ne[j] = cb[nb + tid + j * BLOCK];

        #pragma unroll
        for (int j = 0; j < EPT; ++j) {
            float4 e = ce[j];
            float e2v = __fadd_rn(__fadd_rn(__fadd_rn(__fmul_rn(e.x, e.x),
                                                      __fmul_rn(e.y, e.y)),
                                            __fmul_rn(e.z, e.z)),
                                  __fmul_rn(e.w, e.w));
            int kk = tb + tid + j * BLOCK;
            #pragma unroll
            for (int r = 0; r < ROWS; ++r) {
                float dot = __builtin_fmaf(xr3[r], e.w,
                            __builtin_fmaf(xr2[r], e.z,
                            __builtin_fmaf(xr1[r], e.y,
                            __fmul_rn(xr0[r], e.x))));
                float t1 = __fadd_rn(x2[r], e2v);
                float d  = __builtin_fmaf(dot, -2.0f, t1);
                if (d < best[r]) { best[r] = d; bidx[r] = kk; }
            }
        }

        #pragma unroll
        for (int j = 0; j < EPT; ++j) ce[j] = ne[j];
    }

    // ---- wave-level lexicographic (dist, idx) butterfly reduction
    #pragma unroll
    for (int r = 0; r < ROWS; ++r) {
        float d = best[r]; int i = bidx[r];
        #pragma unroll
        for (int off = 32; off >= 1; off >>= 1) {
            float d2 = __shfl_xor(d, off, 64);
            int   i2 = __shfl_xor(i, off, 64);
            if (d2 < d || (d2 == d && i2 < i)) { d = d2; i = i2; }
        }
        best[r] = d; bidx[r] = i;
    }

    int wave = tid >> 6;
    if ((tid & 63) == 0) {
        #pragma unroll
        for (int r = 0; r < ROWS; ++r) {
            sRD[wave * ROWS + r] = best[r];
            sRI[wave * ROWS + r] = bidx[r];
        }
    }
    __syncthreads();

    if (tid < ROWS) {
        float d = sRD[tid]; int i = sRI[tid];
        #pragma unroll
        for (int w = 1; w < 4; ++w) {
            float d2 = sRD[w * ROWS + tid];
            int   i2 = sRI[w * ROWS + tid];
            if (d2 < d || (d2 == d && i2 < i)) { d = d2; i = i2; }
        }
        out[rowbase + tid] = i;
    }
}

extern "C" void kernel_launch(void* const* d_in, const int* in_sizes, int n_in,
                              void* d_out, int out_size, void* d_ws, size_t ws_size,
                              hipStream_t stream)
{
    const float*  hs = (const float*)d_in[0];    // [1,4,4,48,48]
    const float4* cb = (const float4*)d_in[1];   // [32768,4]
    int* out = (int*)d_out;                      // [9216] int32

    const int nrows = 9216;
    dim3 grid(nrows / ROWS), block(BLOCK);
    vq_argmin_kernel<<<grid, block, 0, stream>>>(hs, cb, out);
}

// Round 4
// 125.041 us; speedup vs baseline: 1.0866x; 1.0142x over previous
//
#include <hip/hip_runtime.h>
#include <cfloat>

// Emu3 VQ-VAE vector quantizer argmin (exact-rounding match to numpy ref):
//   x [9216,4] f32 (channels-last gather from [1,4,4,48,48])
//   e [32768,4] f32
//   out[n] = argmin_k fl( fl(x2+e2) - 2*fl(dot) ), first-min tie semantics.
//
// Round 4: same barrier-free register-streaming as round 3, but:
//  - __launch_bounds__(256, 2): rounds 1-3 showed VGPR_Count 68/52/48 < live
//    value count -> min-waves>=3 capped the allocator and forced AGPR/scratch
//    shuttling (~2x VALU bloat). Budget 256 fits the ~110 live values; at
//    ~110 VGPRs HW occupancy is still 4 waves/SIMD.
//  - ping-pong chunk buffers (2x unrolled loop), no ce=ne register copies.

#define ROWS   9
#define BLOCK  256
#define NK     32768
#define EPT    2                  // codebook entries per lane per chunk
#define CHUNK  (BLOCK * EPT)      // 512 entries per chunk

__global__ __launch_bounds__(BLOCK, 2)
void vq_argmin_kernel(const float* __restrict__ hs,
                      const float4* __restrict__ cb,
                      int* __restrict__ out)
{
    __shared__ float sRD[4 * ROWS];
    __shared__ int   sRI[4 * ROWS];

    const int tid = threadIdx.x;
    const int rowbase = blockIdx.x * ROWS;

    float xr0[ROWS], xr1[ROWS], xr2[ROWS], xr3[ROWS];
    float x2[ROWS];
    float best[ROWS];
    int   bidx[ROWS];

    #pragma unroll
    for (int r = 0; r < ROWS; ++r) {
        int n = rowbase + r;
        int t = n / 2304;                 // 2304 = 48*48
        int rem = n - t * 2304;
        const float* p = hs + t * 9216 + rem;   // + c*2304 per channel
        float a0 = p[0], a1 = p[2304], a2 = p[4608], a3 = p[6912];
        xr0[r] = a0; xr1[r] = a1; xr2[r] = a2; xr3[r] = a3;
        x2[r] = __fadd_rn(__fadd_rn(__fadd_rn(__fmul_rn(a0, a0),
                                              __fmul_rn(a1, a1)),
                                    __fmul_rn(a2, a2)),
                          __fmul_rn(a3, a3));
        best[r] = FLT_MAX;
        bidx[r] = 0;
    }

    float4 bufA[EPT], bufB[EPT];

    auto load_chunk = [&](float4* buf, int tb) {
        #pragma unroll
        for (int j = 0; j < EPT; ++j) buf[j] = cb[tb + tid + j * BLOCK];
    };
    auto compute_chunk = [&](const float4* buf, int tb) {
        #pragma unroll
        for (int j = 0; j < EPT; ++j) {
            float4 e = buf[j];
            float e2v = __fadd_rn(__fadd_rn(__fadd_rn(__fmul_rn(e.x, e.x),
                                                      __fmul_rn(e.y, e.y)),
                                            __fmul_rn(e.z, e.z)),
                                  __fmul_rn(e.w, e.w));
            int kk = tb + tid + j * BLOCK;
            #pragma unroll
            for (int r = 0; r < ROWS; ++r) {
                float dot = __builtin_fmaf(xr3[r], e.w,
                            __builtin_fmaf(xr2[r], e.z,
                            __builtin_fmaf(xr1[r], e.y,
                            __fmul_rn(xr0[r], e.x))));
                float t1 = __fadd_rn(x2[r], e2v);
                float d  = __builtin_fmaf(dot, -2.0f, t1);
                if (d < best[r]) { best[r] = d; bidx[r] = kk; }
            }
        }
    };

    // ---- ping-pong K loop: load one buffer while computing the other
    load_chunk(bufA, 0);
    for (int tb = 0; tb < NK; tb += 2 * CHUNK) {
        load_chunk(bufB, tb + CHUNK);
        compute_chunk(bufA, tb);
        int nb = tb + 2 * CHUNK < NK ? tb + 2 * CHUNK : 0;  // last: dummy reload
        load_chunk(bufA, nb);
        compute_chunk(bufB, tb + CHUNK);
    }

    // ---- wave-level lexicographic (dist, idx) butterfly reduction
    #pragma unroll
    for (int r = 0; r < ROWS; ++r) {
        float d = best[r]; int i = bidx[r];
        #pragma unroll
        for (int off = 32; off >= 1; off >>= 1) {
            float d2 = __shfl_xor(d, off, 64);
            int   i2 = __shfl_xor(i, off, 64);
            if (d2 < d || (d2 == d && i2 < i)) { d = d2; i = i2; }
        }
        best[r] = d; bidx[r] = i;
    }

    int wave = tid >> 6;
    if ((tid & 63) == 0) {
        #pragma unroll
        for (int r = 0; r < ROWS; ++r) {
            sRD[wave * ROWS + r] = best[r];
            sRI[wave * ROWS + r] = bidx[r];
        }
    }
    __syncthreads();

    if (tid < ROWS) {
        float d = sRD[tid]; int i = sRI[tid];
        #pragma unroll
        for (int w = 1; w < 4; ++w) {
            float d2 = sRD[w * ROWS + tid];
            int   i2 = sRI[w * ROWS + tid];
            if (d2 < d || (d2 == d && i2 < i)) { d = d2; i = i2; }
        }
        out[rowbase + tid] = i;
    }
}

extern "C" void kernel_launch(void* const* d_in, const int* in_sizes, int n_in,
                              void* d_out, int out_size, void* d_ws, size_t ws_size,
                              hipStream_t stream)
{
    const float*  hs = (const float*)d_in[0];    // [1,4,4,48,48]
    const float4* cb = (const float4*)d_in[1];   // [32768,4]
    int* out = (int*)d_out;                      // [9216] int32

    const int nrows = 9216;
    dim3 grid(nrows / ROWS), block(BLOCK);
    vq_argmin_kernel<<<grid, block, 0, stream>>>(hs, cb, out);
}

// Round 5
// 121.099 us; speedup vs baseline: 1.1220x; 1.0326x over previous
//
#include <hip/hip_runtime.h>
#include <cfloat>

// Emu3 VQ-VAE vector quantizer argmin (exact-rounding match to numpy ref):
//   x [9216,4] f32 (channels-last gather from [1,4,4,48,48])
//   e [32768,4] f32
//   out[n] = argmin_k fl( fl(x2+e2) - 2*fl(dot) ), first-min tie semantics.
//
// Round 5:
//  - x-components are block-uniform -> readfirstlane into SGPRs (60 values),
//    collapsing VGPR pressure to ~62 so the allocator cannot spill to scratch.
//    (Rounds 1-4: VGPR_Count 48-68 < live count -> scratch spill stalls; VALU
//    tweaks didn't move time -> stall-bound, not issue-bound.)
//  - amdgpu_waves_per_eu(3,4): stop the scheduler's occupancy squeeze at
//    <=128 VGPRs instead of rematerializing/spilling toward 8 waves.
//  - packed fp32 (v_pk_fma_f32 via float2 ext-vectors) over row PAIRS:
//    row data is loop-invariant so packing is free; arithmetic per (row,k)
//    pair drops 6 -> 3 instrs. IEEE-rn identical -> bitwise-same distances.

typedef float v2f __attribute__((ext_vector_type(2)));

#define ROWS  12
#define RP    (ROWS / 2)
#define BLOCK 256
#define NK    32768
#define EPT   2
#define CHUNK (BLOCK * EPT)   // 512

__device__ __forceinline__ float rlf(float v) {
    return __builtin_bit_cast(float,
        __builtin_amdgcn_readfirstlane(__builtin_bit_cast(int, v)));
}

__global__ __launch_bounds__(BLOCK)
__attribute__((amdgpu_waves_per_eu(3, 4)))
void vq_argmin_kernel(const float* __restrict__ hs,
                      const float4* __restrict__ cb,
                      int* __restrict__ out)
{
    __shared__ float sRD[4 * ROWS];
    __shared__ int   sRI[4 * ROWS];

    const int tid = threadIdx.x;
    const int rowbase = blockIdx.x * ROWS;

    v2f xp0[RP], xp1[RP], xp2[RP], xp3[RP], x2p[RP];  // uniform -> SGPR pairs
    float best[ROWS];
    int   bidx[ROWS];   // stores chunk index m; k = m*256 + tid

    #pragma unroll
    for (int p = 0; p < RP; ++p) {
        float c0[2], c1[2], c2[2], c3[2], q[2];
        #pragma unroll
        for (int h = 0; h < 2; ++h) {
            int n = rowbase + 2 * p + h;
            int t = n / 2304;                 // 2304 = 48*48
            int rem = n - t * 2304;
            const float* ptr = hs + t * 9216 + rem;   // + c*2304 per channel
            float a0 = ptr[0], a1 = ptr[2304], a2 = ptr[4608], a3 = ptr[6912];
            c0[h] = a0; c1[h] = a1; c2[h] = a2; c3[h] = a3;
            q[h] = __fadd_rn(__fadd_rn(__fadd_rn(__fmul_rn(a0, a0),
                                                 __fmul_rn(a1, a1)),
                                       __fmul_rn(a2, a2)),
                             __fmul_rn(a3, a3));
        }
        xp0[p] = (v2f){rlf(c0[0]), rlf(c0[1])};
        xp1[p] = (v2f){rlf(c1[0]), rlf(c1[1])};
        xp2[p] = (v2f){rlf(c2[0]), rlf(c2[1])};
        xp3[p] = (v2f){rlf(c3[0]), rlf(c3[1])};
        x2p[p] = (v2f){rlf(q[0]),  rlf(q[1])};
    }
    #pragma unroll
    for (int r = 0; r < ROWS; ++r) { best[r] = FLT_MAX; bidx[r] = 0; }

    float4 bufA[EPT], bufB[EPT];

    auto load_chunk = [&](float4* buf, int tb) {
        #pragma unroll
        for (int j = 0; j < EPT; ++j) buf[j] = cb[tb + tid + j * BLOCK];
    };
    auto compute_chunk = [&](const float4* buf, int tb) {
        #pragma unroll
        for (int j = 0; j < EPT; ++j) {
            float4 e = buf[j];
            float e2 = __fadd_rn(__fadd_rn(__fadd_rn(__fmul_rn(e.x, e.x),
                                                     __fmul_rn(e.y, e.y)),
                                           __fmul_rn(e.z, e.z)),
                                 __fmul_rn(e.w, e.w));
            v2f ex = {e.x, e.x}, ey = {e.y, e.y};
            v2f ez = {e.z, e.z}, ew = {e.w, e.w};
            v2f e2s = {e2, e2};
            int m = tb / BLOCK + j;           // uniform chunk index
            #pragma unroll
            for (int p = 0; p < RP; ++p) {
                v2f dot = xp0[p] * ex;
                dot = __builtin_elementwise_fma(xp1[p], ey, dot);
                dot = __builtin_elementwise_fma(xp2[p], ez, dot);
                dot = __builtin_elementwise_fma(xp3[p], ew, dot);
                v2f t1 = x2p[p] + e2s;
                v2f d  = __builtin_elementwise_fma(dot, (v2f){-2.f, -2.f}, t1);
                if (d.x < best[2 * p])     { best[2 * p] = d.x;     bidx[2 * p] = m; }
                if (d.y < best[2 * p + 1]) { best[2 * p + 1] = d.y; bidx[2 * p + 1] = m; }
            }
        }
    };

    // ---- ping-pong K loop: load one buffer while computing the other
    load_chunk(bufA, 0);
    for (int tb = 0; tb < NK; tb += 2 * CHUNK) {
        load_chunk(bufB, tb + CHUNK);
        compute_chunk(bufA, tb);
        int nb = tb + 2 * CHUNK < NK ? tb + 2 * CHUNK : 0;  // last: dummy reload
        load_chunk(bufA, nb);
        compute_chunk(bufB, tb + CHUNK);
    }

    // ---- expand chunk index -> full codebook index, then reduce
    int kk[ROWS];
    #pragma unroll
    for (int r = 0; r < ROWS; ++r) kk[r] = bidx[r] * BLOCK + tid;

    // wave-level lexicographic (dist, idx) butterfly reduction
    #pragma unroll
    for (int r = 0; r < ROWS; ++r) {
        float d = best[r]; int i = kk[r];
        #pragma unroll
        for (int off = 32; off >= 1; off >>= 1) {
            float d2 = __shfl_xor(d, off, 64);
            int   i2 = __shfl_xor(i, off, 64);
            if (d2 < d || (d2 == d && i2 < i)) { d = d2; i = i2; }
        }
        best[r] = d; kk[r] = i;
    }

    int wave = tid >> 6;
    if ((tid & 63) == 0) {
        #pragma unroll
        for (int r = 0; r < ROWS; ++r) {
            sRD[wave * ROWS + r] = best[r];
            sRI[wave * ROWS + r] = kk[r];
        }
    }
    __syncthreads();

    if (tid < ROWS) {
        float d = sRD[tid]; int i = sRI[tid];
        #pragma unroll
        for (int w = 1; w < 4; ++w) {
            float d2 = sRD[w * ROWS + tid];
            int   i2 = sRI[w * ROWS + tid];
            if (d2 < d || (d2 == d && i2 < i)) { d = d2; i = i2; }
        }
        out[rowbase + tid] = i;
    }
}

extern "C" void kernel_launch(void* const* d_in, const int* in_sizes, int n_in,
                              void* d_out, int out_size, void* d_ws, size_t ws_size,
                              hipStream_t stream)
{
    const float*  hs = (const float*)d_in[0];    // [1,4,4,48,48]
    const float4* cb = (const float4*)d_in[1];   // [32768,4]
    int* out = (int*)d_out;                      // [9216] int32

    const int nrows = 9216;
    dim3 grid(nrows / ROWS), block(BLOCK);
    vq_argmin_kernel<<<grid, block, 0, stream>>>(hs, cb, out);
}